// Round 1
// baseline (375.981 us; speedup 1.0000x reference)
//
#include <hip/hip_runtime.h>
#include <math.h>

#define TPB 256

// ---------------- degree histogram / dinv ----------------
__global__ __launch_bounds__(TPB) void k_hist(const int* __restrict__ dst,
                                              int* __restrict__ cnt, int E) {
  int e = blockIdx.x * TPB + threadIdx.x;
  if (e < E) atomicAdd(&cnt[dst[e]], 1);
}

__global__ __launch_bounds__(TPB) void k_dinv(const int* __restrict__ cnt,
                                              float* __restrict__ dinv, int N) {
  int i = blockIdx.x * TPB + threadIdx.x;
  if (i < N) dinv[i] = rsqrtf((float)(cnt[i] + 1));  // +1 self-loop
}

// ---------------- exclusive scan over counts (CSR row_ptr) ----------------
__global__ __launch_bounds__(TPB) void k_scan1(const int* __restrict__ cnt,
                                               int* __restrict__ part, int N) {
  __shared__ int red[TPB];
  int t = threadIdx.x;
  int base = blockIdx.x * 1024 + t * 4;
  int s = 0;
#pragma unroll
  for (int u = 0; u < 4; ++u) { int g = base + u; if (g < N) s += cnt[g]; }
  red[t] = s;
  __syncthreads();
  for (int o = TPB / 2; o > 0; o >>= 1) {
    if (t < o) red[t] += red[t + o];
    __syncthreads();
  }
  if (t == 0) part[blockIdx.x] = red[0];
}

__global__ void k_scan2(int* part, int nb) {
  if (threadIdx.x == 0) {
    int s = 0;
    for (int i = 0; i < nb; ++i) { int v = part[i]; part[i] = s; s += v; }
  }
}

__global__ __launch_bounds__(TPB) void k_scan3(const int* __restrict__ cnt,
                                               const int* __restrict__ part,
                                               int* __restrict__ rowptr,
                                               int* __restrict__ cursor, int N, int E) {
  __shared__ int tsum[TPB];
  int t = threadIdx.x;
  int base = blockIdx.x * 1024 + t * 4;
  int v[4], pre[4], s = 0;
#pragma unroll
  for (int u = 0; u < 4; ++u) {
    int g = base + u;
    v[u] = (g < N) ? cnt[g] : 0;
    pre[u] = s;
    s += v[u];
  }
  tsum[t] = s;
  __syncthreads();
  for (int o = 1; o < TPB; o <<= 1) {  // Hillis-Steele inclusive scan
    int xv = (t >= o) ? tsum[t - o] : 0;
    __syncthreads();
    tsum[t] += xv;
    __syncthreads();
  }
  int excl = tsum[t] - s;
  int boff = part[blockIdx.x];
#pragma unroll
  for (int u = 0; u < 4; ++u) {
    int g = base + u;
    if (g < N) {
      int r = boff + excl + pre[u];
      rowptr[g] = r;
      cursor[g] = r;
    }
  }
  if (blockIdx.x == 0 && t == 0) rowptr[N] = E;
}

__global__ __launch_bounds__(TPB) void k_fill(const int* __restrict__ src,
                                              const int* __restrict__ dst,
                                              int* __restrict__ cursor,
                                              int* __restrict__ col, int E) {
  int e = blockIdx.x * TPB + threadIdx.x;
  if (e < E) {
    int p = atomicAdd(&cursor[dst[e]], 1);
    col[p] = src[e];
  }
}

// ---------------- GEMM: H[N,64] = X[N,K] @ W[K,64] ----------------
template <int K>
__global__ __launch_bounds__(TPB) void k_gemm(const float* __restrict__ X,
                                              const float* __restrict__ W,
                                              float* __restrict__ H, int N) {
  __shared__ float sW[K * 64];
  __shared__ float sX[16 * (K + 4)];  // +4 pad: breaks 4-way bank conflict across node groups
  int tid = threadIdx.x;
  for (int i = tid; i < K * 64; i += TPB) sW[i] = W[i];
  int nq = tid >> 4;         // node within 16-tile
  int fq = (tid & 15) * 4;   // feature quad
  for (int tile = blockIdx.x * 16; tile < N; tile += gridDim.x * 16) {
    __syncthreads();
    for (int i = tid; i < 16 * K; i += TPB) {
      int r = i / K, c = i % K;
      int g = tile + r;
      sX[r * (K + 4) + c] = (g < N) ? X[(size_t)g * K + c] : 0.f;
    }
    __syncthreads();
    int node = tile + nq;
    if (node < N) {
      float4 acc = {0.f, 0.f, 0.f, 0.f};
#pragma unroll 4
      for (int k = 0; k < K; ++k) {
        float xv = sX[nq * (K + 4) + k];
        float4 wv = *(const float4*)&sW[k * 64 + fq];
        acc.x += xv * wv.x;
        acc.y += xv * wv.y;
        acc.z += xv * wv.z;
        acc.w += xv * wv.w;
      }
      *(float4*)&H[(size_t)node * 64 + fq] = acc;
    }
  }
}

// ---------------- pull aggregation: one wave per node, lane = feature ----------------
__global__ __launch_bounds__(TPB) void k_agg(const float* __restrict__ H,
                                             const int* __restrict__ rowptr,
                                             const int* __restrict__ col,
                                             const float* __restrict__ dinv,
                                             const float* __restrict__ bias,
                                             float* __restrict__ OUT, int N) {
  int i = (blockIdx.x * TPB + threadIdx.x) >> 6;
  int lane = threadIdx.x & 63;
  if (i >= N) return;
  float di = dinv[i];
  float acc = H[(size_t)i * 64 + lane] * di * di;  // self-loop
  int beg = rowptr[i], end = rowptr[i + 1];
  for (int c0 = beg; c0 < end; c0 += 64) {
    int m = end - c0;
    if (m > 64) m = 64;
    // edge-parallel metadata load (breaks the serial col->dinv latency chain)
    int jj = c0 + lane;
    int sv = col[jj < end ? jj : beg];
    float nv = di * dinv[sv];
    for (int t = 0; t < m; ++t) {
      int s = __shfl(sv, t);
      float nm = __shfl(nv, t);
      acc += H[(size_t)s * 64 + lane] * nm;  // coalesced 256B per edge
    }
  }
  acc += bias[lane];
  OUT[(size_t)i * 64 + lane] = tanhf(acc);
}

// ---------------- fused MLP head: tanh(A@W1+b1)@W2+b2 ----------------
__global__ __launch_bounds__(TPB) void k_fc(const float* __restrict__ A,
                                            const float* __restrict__ w1,
                                            const float* __restrict__ b1,
                                            const float* __restrict__ w2,
                                            const float* __restrict__ b2,
                                            float* __restrict__ out, int N) {
  __shared__ float sw1t[32 * 64];  // transposed: [j][k] so inner loop is contiguous
  __shared__ float sb1[32];
  __shared__ float sw2[32];
  __shared__ float sA[128 * 65];   // +1 pad, conflict-free per-row reads
  int tid = threadIdx.x;
  for (int i = tid; i < 32 * 64; i += TPB) {
    int j = i >> 6, k = i & 63;
    sw1t[i] = w1[k * 32 + j];
  }
  if (tid < 32) { sb1[tid] = b1[tid]; sw2[tid] = w2[tid]; }
  int base = blockIdx.x * 128;
  for (int i = tid; i < 128 * 64; i += TPB) {
    int r = i >> 6, c = i & 63;
    int g = base + r;
    sA[r * 65 + c] = (g < N) ? A[(size_t)g * 64 + c] : 0.f;
  }
  __syncthreads();
  int r = tid >> 1, q = tid & 1;  // 2 threads per node, split the 32 hidden units
  int node = base + r;
  const float* arow = &sA[r * 65];
  float o = 0.f;
  for (int j = q * 16; j < q * 16 + 16; ++j) {
    float accj = sb1[j];
    const float* wrow = &sw1t[j * 64];
#pragma unroll 8
    for (int k = 0; k < 64; ++k) accj += arow[k] * wrow[k];
    o += tanhf(accj) * sw2[j];
  }
  o += __shfl_xor(o, 1);
  if (q == 0 && node < N) out[node] = o + b2[0];
}

extern "C" void kernel_launch(void* const* d_in, const int* in_sizes, int n_in,
                              void* d_out, int out_size, void* d_ws, size_t ws_size,
                              hipStream_t stream) {
  const float* x   = (const float*)d_in[0];
  const int*   ei  = (const int*)d_in[1];
  const float* w1  = (const float*)d_in[2];
  const float* b1  = (const float*)d_in[3];
  const float* w2  = (const float*)d_in[4];
  const float* b2  = (const float*)d_in[5];
  const float* fw1 = (const float*)d_in[6];
  const float* fb1 = (const float*)d_in[7];
  const float* fw2 = (const float*)d_in[8];
  const float* fb2 = (const float*)d_in[9];
  float* out = (float*)d_out;

  int N = in_sizes[0] / 128;
  int E = in_sizes[1] / 2;
  const int* src = ei;
  const int* dst = ei + E;

  // workspace carve-up (~30 MB total)
  char* p = (char*)d_ws;
  size_t off = 0;
  auto take = [&](size_t bytes) -> void* {
    void* r = p + off;
    off += (bytes + 255) & ~(size_t)255;
    return r;
  };
  int*   cnt    = (int*)take((size_t)N * 4);
  float* dinv   = (float*)take((size_t)N * 4);
  int*   rowptr = (int*)take((size_t)(N + 1) * 4);
  int*   cursor = (int*)take((size_t)N * 4);
  int*   part   = (int*)take(64 * 4);
  int*   col    = (int*)take((size_t)E * 4);
  float* h      = (float*)take((size_t)N * 64 * 4);
  float* a      = (float*)take((size_t)N * 64 * 4);
  (void)ws_size; (void)n_in; (void)out_size;

  int nbE = (E + TPB - 1) / TPB;
  int nbN = (N + TPB - 1) / TPB;
  int NB  = (N + 1023) / 1024;  // scan blocks (49 for N=50000), part[] holds 64

  hipMemsetAsync(cnt, 0, (size_t)N * 4, stream);
  k_hist<<<nbE, TPB, 0, stream>>>(dst, cnt, E);
  k_dinv<<<nbN, TPB, 0, stream>>>(cnt, dinv, N);
  k_scan1<<<NB, TPB, 0, stream>>>(cnt, part, N);
  k_scan2<<<1, 64, 0, stream>>>(part, NB);
  k_scan3<<<NB, TPB, 0, stream>>>(cnt, part, rowptr, cursor, N, E);
  k_fill<<<nbE, TPB, 0, stream>>>(src, dst, cursor, col, E);

  k_gemm<128><<<(N + 15) / 16, TPB, 0, stream>>>(x, w1, h, N);
  k_agg<<<(N + 3) / 4, TPB, 0, stream>>>(h, rowptr, col, dinv, b1, a, N);
  k_gemm<64><<<(N + 15) / 16, TPB, 0, stream>>>(a, w2, h, N);
  k_agg<<<(N + 3) / 4, TPB, 0, stream>>>(h, rowptr, col, dinv, b2, a, N);
  k_fc<<<(N + 127) / 128, TPB, 0, stream>>>(a, fw1, fb1, fw2, fb2, out, N);
}

// Round 2
// 329.111 us; speedup vs baseline: 1.1424x; 1.1424x over previous
//
#include <hip/hip_runtime.h>
#include <math.h>

#define TPB 256

// ---------------- degree histogram / dinv ----------------
__global__ __launch_bounds__(TPB) void k_hist(const int* __restrict__ dst,
                                              int* __restrict__ cnt, int E) {
  int e = blockIdx.x * TPB + threadIdx.x;
  if (e < E) atomicAdd(&cnt[dst[e]], 1);
}

__global__ __launch_bounds__(TPB) void k_dinv(const int* __restrict__ cnt,
                                              float* __restrict__ dinv, int N) {
  int i = blockIdx.x * TPB + threadIdx.x;
  if (i < N) dinv[i] = rsqrtf((float)(cnt[i] + 1));  // +1 self-loop
}

// ---------------- exclusive scan over counts (CSR row_ptr) ----------------
__global__ __launch_bounds__(TPB) void k_scan1(const int* __restrict__ cnt,
                                               int* __restrict__ part, int N) {
  __shared__ int red[TPB];
  int t = threadIdx.x;
  int base = blockIdx.x * 1024 + t * 4;
  int s = 0;
#pragma unroll
  for (int u = 0; u < 4; ++u) { int g = base + u; if (g < N) s += cnt[g]; }
  red[t] = s;
  __syncthreads();
  for (int o = TPB / 2; o > 0; o >>= 1) {
    if (t < o) red[t] += red[t + o];
    __syncthreads();
  }
  if (t == 0) part[blockIdx.x] = red[0];
}

__global__ void k_scan2(int* part, int nb) {
  if (threadIdx.x == 0) {
    int s = 0;
    for (int i = 0; i < nb; ++i) { int v = part[i]; part[i] = s; s += v; }
  }
}

__global__ __launch_bounds__(TPB) void k_scan3(const int* __restrict__ cnt,
                                               const int* __restrict__ part,
                                               int* __restrict__ rowptr,
                                               int* __restrict__ cursor, int N, int E) {
  __shared__ int tsum[TPB];
  int t = threadIdx.x;
  int base = blockIdx.x * 1024 + t * 4;
  int v[4], pre[4], s = 0;
#pragma unroll
  for (int u = 0; u < 4; ++u) {
    int g = base + u;
    v[u] = (g < N) ? cnt[g] : 0;
    pre[u] = s;
    s += v[u];
  }
  tsum[t] = s;
  __syncthreads();
  for (int o = 1; o < TPB; o <<= 1) {  // Hillis-Steele inclusive scan
    int xv = (t >= o) ? tsum[t - o] : 0;
    __syncthreads();
    tsum[t] += xv;
    __syncthreads();
  }
  int excl = tsum[t] - s;
  int boff = part[blockIdx.x];
#pragma unroll
  for (int u = 0; u < 4; ++u) {
    int g = base + u;
    if (g < N) {
      int r = boff + excl + pre[u];
      rowptr[g] = r;
      cursor[g] = r;
    }
  }
  if (blockIdx.x == 0 && t == 0) rowptr[N] = E;
}

__global__ __launch_bounds__(TPB) void k_fill(const int* __restrict__ src,
                                              const int* __restrict__ dst,
                                              int* __restrict__ cursor,
                                              int* __restrict__ col, int E) {
  int e = blockIdx.x * TPB + threadIdx.x;
  if (e < E) {
    int p = atomicAdd(&cursor[dst[e]], 1);
    col[p] = src[e];
  }
}

// ---------------- GEMM: H[N,64] = X[N,K] @ W[K,64] ----------------
// Launched with a small fixed grid: each block grid-strides over many 16-node
// tiles so the 32KB W staging load is amortized (3125-block launch re-read W
// per block: 100MB through L2).
template <int K>
__global__ __launch_bounds__(TPB) void k_gemm(const float* __restrict__ X,
                                              const float* __restrict__ W,
                                              float* __restrict__ H, int N) {
  __shared__ float sW[K * 64];
  __shared__ float sX[16 * (K + 4)];
  int tid = threadIdx.x;
  for (int i = tid; i < K * 64; i += TPB) sW[i] = W[i];
  int nq = tid >> 4;         // node within 16-tile
  int fq = (tid & 15) * 4;   // feature quad
  for (int tile = blockIdx.x * 16; tile < N; tile += gridDim.x * 16) {
    __syncthreads();
    for (int i = tid; i < 16 * K; i += TPB) {
      int r = i / K, c = i % K;
      int g = tile + r;
      sX[r * (K + 4) + c] = (g < N) ? X[(size_t)g * K + c] : 0.f;
    }
    __syncthreads();
    int node = tile + nq;
    if (node < N) {
      float4 acc = {0.f, 0.f, 0.f, 0.f};
#pragma unroll 4
      for (int k = 0; k < K; ++k) {
        float xv = sX[nq * (K + 4) + k];
        float4 wv = *(const float4*)&sW[k * 64 + fq];
        acc.x += xv * wv.x;
        acc.y += xv * wv.y;
        acc.z += xv * wv.z;
        acc.w += xv * wv.w;
      }
      *(float4*)&H[(size_t)node * 64 + fq] = acc;
    }
  }
}

// ---------------- pull aggregation: one wave per node, lane = feature ----------------
// 8-way edge batching: readlane (scalar broadcast, no LDS round-trip) gives 8
// independent SGPR-based gathers in flight per wave to hide LLC latency.
__device__ __forceinline__ float rl_f(float v, int l) {
  return __int_as_float(__builtin_amdgcn_readlane(__float_as_int(v), l));
}

__global__ __launch_bounds__(TPB) void k_agg(const float* __restrict__ H,
                                             const int* __restrict__ rowptr,
                                             const int* __restrict__ col,
                                             const float* __restrict__ dinv,
                                             const float* __restrict__ bias,
                                             float* __restrict__ OUT, int N) {
  int i = (blockIdx.x * TPB + threadIdx.x) >> 6;
  int lane = threadIdx.x & 63;
  if (i >= N) return;
  float di = dinv[i];
  float acc = H[(size_t)i * 64 + lane] * di * di;  // self-loop
  int beg = rowptr[i], end = rowptr[i + 1];
  for (int c0 = beg; c0 < end; c0 += 64) {
    int m = end - c0;
    if (m > 64) m = 64;
    // edge-parallel metadata load across lanes
    int jj = c0 + lane;
    int sv = col[jj < end ? jj : beg];
    float nv = di * dinv[sv];
    int t = 0;
    for (; t + 8 <= m; t += 8) {
      int s0 = __builtin_amdgcn_readlane(sv, t + 0);
      int s1 = __builtin_amdgcn_readlane(sv, t + 1);
      int s2 = __builtin_amdgcn_readlane(sv, t + 2);
      int s3 = __builtin_amdgcn_readlane(sv, t + 3);
      int s4 = __builtin_amdgcn_readlane(sv, t + 4);
      int s5 = __builtin_amdgcn_readlane(sv, t + 5);
      int s6 = __builtin_amdgcn_readlane(sv, t + 6);
      int s7 = __builtin_amdgcn_readlane(sv, t + 7);
      float h0 = H[((size_t)s0 << 6) + lane];
      float h1 = H[((size_t)s1 << 6) + lane];
      float h2 = H[((size_t)s2 << 6) + lane];
      float h3 = H[((size_t)s3 << 6) + lane];
      float h4 = H[((size_t)s4 << 6) + lane];
      float h5 = H[((size_t)s5 << 6) + lane];
      float h6 = H[((size_t)s6 << 6) + lane];
      float h7 = H[((size_t)s7 << 6) + lane];
      acc += h0 * rl_f(nv, t + 0);
      acc += h1 * rl_f(nv, t + 1);
      acc += h2 * rl_f(nv, t + 2);
      acc += h3 * rl_f(nv, t + 3);
      acc += h4 * rl_f(nv, t + 4);
      acc += h5 * rl_f(nv, t + 5);
      acc += h6 * rl_f(nv, t + 6);
      acc += h7 * rl_f(nv, t + 7);
    }
    if (t + 4 <= m) {
      int s0 = __builtin_amdgcn_readlane(sv, t + 0);
      int s1 = __builtin_amdgcn_readlane(sv, t + 1);
      int s2 = __builtin_amdgcn_readlane(sv, t + 2);
      int s3 = __builtin_amdgcn_readlane(sv, t + 3);
      float h0 = H[((size_t)s0 << 6) + lane];
      float h1 = H[((size_t)s1 << 6) + lane];
      float h2 = H[((size_t)s2 << 6) + lane];
      float h3 = H[((size_t)s3 << 6) + lane];
      acc += h0 * rl_f(nv, t + 0);
      acc += h1 * rl_f(nv, t + 1);
      acc += h2 * rl_f(nv, t + 2);
      acc += h3 * rl_f(nv, t + 3);
      t += 4;
    }
    for (; t < m; ++t) {
      int s = __builtin_amdgcn_readlane(sv, t);
      acc += H[((size_t)s << 6) + lane] * rl_f(nv, t);
    }
  }
  acc += bias[lane];
  OUT[(size_t)i * 64 + lane] = tanhf(acc);
}

// ---------------- fused MLP head: tanh(A@W1+b1)@W2+b2 ----------------
__global__ __launch_bounds__(TPB) void k_fc(const float* __restrict__ A,
                                            const float* __restrict__ w1,
                                            const float* __restrict__ b1,
                                            const float* __restrict__ w2,
                                            const float* __restrict__ b2,
                                            float* __restrict__ out, int N) {
  __shared__ float sw1t[32 * 64];  // transposed: [j][k] so inner loop is contiguous
  __shared__ float sb1[32];
  __shared__ float sw2[32];
  __shared__ float sA[128 * 65];   // +1 pad, conflict-free per-row reads
  int tid = threadIdx.x;
  for (int i = tid; i < 32 * 64; i += TPB) {
    int j = i >> 6, k = i & 63;
    sw1t[i] = w1[k * 32 + j];
  }
  if (tid < 32) { sb1[tid] = b1[tid]; sw2[tid] = w2[tid]; }
  int base = blockIdx.x * 128;
  for (int i = tid; i < 128 * 64; i += TPB) {
    int r = i >> 6, c = i & 63;
    int g = base + r;
    sA[r * 65 + c] = (g < N) ? A[(size_t)g * 64 + c] : 0.f;
  }
  __syncthreads();
  int r = tid >> 1, q = tid & 1;  // 2 threads per node, split the 32 hidden units
  int node = base + r;
  const float* arow = &sA[r * 65];
  float o = 0.f;
  for (int j = q * 16; j < q * 16 + 16; ++j) {
    float accj = sb1[j];
    const float* wrow = &sw1t[j * 64];
#pragma unroll 8
    for (int k = 0; k < 64; ++k) accj += arow[k] * wrow[k];
    o += tanhf(accj) * sw2[j];
  }
  o += __shfl_xor(o, 1);
  if (q == 0 && node < N) out[node] = o + b2[0];
}

extern "C" void kernel_launch(void* const* d_in, const int* in_sizes, int n_in,
                              void* d_out, int out_size, void* d_ws, size_t ws_size,
                              hipStream_t stream) {
  const float* x   = (const float*)d_in[0];
  const int*   ei  = (const int*)d_in[1];
  const float* w1  = (const float*)d_in[2];
  const float* b1  = (const float*)d_in[3];
  const float* w2  = (const float*)d_in[4];
  const float* b2  = (const float*)d_in[5];
  const float* fw1 = (const float*)d_in[6];
  const float* fb1 = (const float*)d_in[7];
  const float* fw2 = (const float*)d_in[8];
  const float* fb2 = (const float*)d_in[9];
  float* out = (float*)d_out;

  int N = in_sizes[0] / 128;
  int E = in_sizes[1] / 2;
  const int* src = ei;
  const int* dst = ei + E;

  // workspace carve-up (~30 MB total)
  char* p = (char*)d_ws;
  size_t off = 0;
  auto take = [&](size_t bytes) -> void* {
    void* r = p + off;
    off += (bytes + 255) & ~(size_t)255;
    return r;
  };
  int*   cnt    = (int*)take((size_t)N * 4);
  float* dinv   = (float*)take((size_t)N * 4);
  int*   rowptr = (int*)take((size_t)(N + 1) * 4);
  int*   cursor = (int*)take((size_t)N * 4);
  int*   part   = (int*)take(64 * 4);
  int*   col    = (int*)take((size_t)E * 4);
  float* h      = (float*)take((size_t)N * 64 * 4);
  float* a      = (float*)take((size_t)N * 64 * 4);
  (void)ws_size; (void)n_in; (void)out_size;

  int nbE = (E + TPB - 1) / TPB;
  int nbN = (N + TPB - 1) / TPB;
  int NB  = (N + 1023) / 1024;  // scan blocks (49 for N=50000), part[] holds 64

  hipMemsetAsync(cnt, 0, (size_t)N * 4, stream);
  k_hist<<<nbE, TPB, 0, stream>>>(dst, cnt, E);
  k_dinv<<<nbN, TPB, 0, stream>>>(cnt, dinv, N);
  k_scan1<<<NB, TPB, 0, stream>>>(cnt, part, N);
  k_scan2<<<1, 64, 0, stream>>>(part, NB);
  k_scan3<<<NB, TPB, 0, stream>>>(cnt, part, rowptr, cursor, N, E);
  k_fill<<<nbE, TPB, 0, stream>>>(src, dst, cursor, col, E);

  k_gemm<128><<<640, TPB, 0, stream>>>(x, w1, h, N);
  k_agg<<<(N + 3) / 4, TPB, 0, stream>>>(h, rowptr, col, dinv, b1, a, N);
  k_gemm<64><<<640, TPB, 0, stream>>>(a, w2, h, N);
  k_agg<<<(N + 3) / 4, TPB, 0, stream>>>(h, rowptr, col, dinv, b2, a, N);
  k_fc<<<(N + 127) / 128, TPB, 0, stream>>>(a, fw1, fb1, fw2, fb2, out, N);
}

// Round 3
// 273.576 us; speedup vs baseline: 1.3743x; 1.2030x over previous
//
#include <hip/hip_runtime.h>
#include <math.h>

#define TPB 256
#define NBK_MAX 512   // max dst buckets (128 nodes each)
#define FILL_CAP 4096 // LDS col-buffer capacity per bucket (avg run = 2048, std ~45)

// ---------------- pass A: per-block bucket histogram ----------------
__global__ __launch_bounds__(TPB) void k_bcount(const int* __restrict__ dst,
                                                int* __restrict__ bh, int E, int NBK) {
  __shared__ int h[NBK_MAX];
  int tid = threadIdx.x, blk = blockIdx.x, G = gridDim.x;
  for (int b = tid; b < NBK; b += TPB) h[b] = 0;
  __syncthreads();
  int chunk = (E + G - 1) / G, lo = blk * chunk, hi = min(E, lo + chunk);
  for (int e = lo + tid; e < hi; e += TPB) atomicAdd(&h[dst[e] >> 7], 1);
  __syncthreads();
  for (int b = tid; b < NBK; b += TPB) bh[b * G + blk] = h[b];  // bucket-major
}

// ---------------- exclusive scan (used for bh and for cnt->rowptr) ----------------
__global__ __launch_bounds__(TPB) void k_scan1(const int* __restrict__ cnt,
                                               int* __restrict__ part, int N) {
  __shared__ int red[TPB];
  int t = threadIdx.x;
  int base = blockIdx.x * 1024 + t * 4;
  int s = 0;
#pragma unroll
  for (int u = 0; u < 4; ++u) { int g = base + u; if (g < N) s += cnt[g]; }
  red[t] = s;
  __syncthreads();
  for (int o = TPB / 2; o > 0; o >>= 1) {
    if (t < o) red[t] += red[t + o];
    __syncthreads();
  }
  if (t == 0) part[blockIdx.x] = red[0];
}

__global__ void k_scan2(int* part, int nb) {
  if (threadIdx.x == 0) {
    int s = 0;
    for (int i = 0; i < nb; ++i) { int v = part[i]; part[i] = s; s += v; }
  }
}

__global__ __launch_bounds__(TPB) void k_scan3(const int* __restrict__ cnt,
                                               const int* __restrict__ part,
                                               int* __restrict__ rowptr,
                                               int* __restrict__ cursor, int N, int E) {
  __shared__ int tsum[TPB];
  int t = threadIdx.x;
  int base = blockIdx.x * 1024 + t * 4;
  int v[4], pre[4], s = 0;
#pragma unroll
  for (int u = 0; u < 4; ++u) {
    int g = base + u;
    v[u] = (g < N) ? cnt[g] : 0;
    pre[u] = s;
    s += v[u];
  }
  tsum[t] = s;
  __syncthreads();
  for (int o = 1; o < TPB; o <<= 1) {  // Hillis-Steele inclusive scan
    int xv = (t >= o) ? tsum[t - o] : 0;
    __syncthreads();
    tsum[t] += xv;
    __syncthreads();
  }
  int excl = tsum[t] - s;
  int boff = part[blockIdx.x];
#pragma unroll
  for (int u = 0; u < 4; ++u) {
    int g = base + u;
    if (g < N) {
      int r = boff + excl + pre[u];
      rowptr[g] = r;
      cursor[g] = r;
    }
  }
  if (blockIdx.x == 0 && t == 0) rowptr[N] = E;
}

// ---------------- pass B: scatter edges into bucket-grouped e2 ----------------
// e2 entry = (src << 7) | (dst & 127). Each (bucket,block) run is written by
// exactly one block -> no cross-XCD line ping-pong.
__global__ __launch_bounds__(TPB) void k_bscatter(const int* __restrict__ src,
                                                  const int* __restrict__ dst,
                                                  const int* __restrict__ bh_off,
                                                  unsigned* __restrict__ e2,
                                                  int E, int NBK) {
  __shared__ int cur[NBK_MAX];
  int tid = threadIdx.x, blk = blockIdx.x, G = gridDim.x;
  for (int b = tid; b < NBK; b += TPB) cur[b] = bh_off[b * G + blk];
  __syncthreads();
  int chunk = (E + G - 1) / G, lo = blk * chunk, hi = min(E, lo + chunk);
  for (int e = lo + tid; e < hi; e += TPB) {
    int d = dst[e], s = src[e];
    int p = atomicAdd(&cur[d >> 7], 1);
    e2[p] = ((unsigned)s << 7) | (unsigned)(d & 127);
  }
}

// ---------------- per-bucket degree count + dinv (replaces global-atomic hist) ----------------
__global__ __launch_bounds__(TPB) void k_cnt(const unsigned* __restrict__ e2,
                                             const int* __restrict__ bh_off,
                                             int* __restrict__ cnt,
                                             float* __restrict__ dinv,
                                             int N, int G) {
  __shared__ int c[128];
  int tid = threadIdx.x, b = blockIdx.x;
  if (tid < 128) c[tid] = 0;
  __syncthreads();
  int st = bh_off[b * G], en = bh_off[(b + 1) * G];
  for (int i = st + tid; i < en; i += TPB) atomicAdd(&c[e2[i] & 127u], 1);
  __syncthreads();
  if (tid < 128) {
    int node = b * 128 + tid;
    if (node < N) {
      cnt[node] = c[tid];
      dinv[node] = rsqrtf((float)(c[tid] + 1));  // +1 self-loop
    }
  }
}

// ---------------- final CSR fill: LDS scatter, coalesced global dump ----------------
__global__ __launch_bounds__(TPB) void k_fill2(const unsigned* __restrict__ e2,
                                               const int* __restrict__ rowptr,
                                               int* __restrict__ cursor,
                                               int* __restrict__ col, int N) {
  __shared__ int cur[128];
  __shared__ int buf[FILL_CAP];
  int tid = threadIdx.x, b = blockIdx.x;
  int st = rowptr[min(b * 128, N)];
  int en = rowptr[min((b + 1) * 128, N)];
  int len = en - st;
  if (len <= FILL_CAP) {
    if (tid < 128) cur[tid] = rowptr[min(b * 128 + tid, N)] - st;
    __syncthreads();
    for (int i = st + tid; i < en; i += TPB) {
      unsigned v = e2[i];
      int p = atomicAdd(&cur[v & 127u], 1);
      buf[p] = (int)(v >> 7);
    }
    __syncthreads();
    for (int i = tid; i < len; i += TPB) col[st + i] = buf[i];
  } else {  // safety fallback (never expected for this distribution)
    for (int i = st + tid; i < en; i += TPB) {
      unsigned v = e2[i];
      int node = b * 128 + (int)(v & 127u);
      int p = atomicAdd(&cursor[node], 1);
      col[p] = (int)(v >> 7);
    }
  }
}

// ---------------- GEMM: H[N,64] = X[N,K] @ W[K,64] ----------------
template <int K>
__global__ __launch_bounds__(TPB) void k_gemm(const float* __restrict__ X,
                                              const float* __restrict__ W,
                                              float* __restrict__ H, int N) {
  __shared__ float sW[K * 64];
  __shared__ float sX[16 * (K + 4)];
  int tid = threadIdx.x;
  for (int i = tid; i < K * 64; i += TPB) sW[i] = W[i];
  int nq = tid >> 4;         // node within 16-tile
  int fq = (tid & 15) * 4;   // feature quad
  for (int tile = blockIdx.x * 16; tile < N; tile += gridDim.x * 16) {
    __syncthreads();
    for (int i = tid; i < 16 * K; i += TPB) {
      int r = i / K, c = i % K;
      int g = tile + r;
      sX[r * (K + 4) + c] = (g < N) ? X[(size_t)g * K + c] : 0.f;
    }
    __syncthreads();
    int node = tile + nq;
    if (node < N) {
      float4 acc = {0.f, 0.f, 0.f, 0.f};
#pragma unroll 4
      for (int k = 0; k < K; ++k) {
        float xv = sX[nq * (K + 4) + k];
        float4 wv = *(const float4*)&sW[k * 64 + fq];
        acc.x += xv * wv.x;
        acc.y += xv * wv.y;
        acc.z += xv * wv.z;
        acc.w += xv * wv.w;
      }
      *(float4*)&H[(size_t)node * 64 + fq] = acc;
    }
  }
}

// ---------------- pull aggregation: one wave per node, lane = feature ----------------
__device__ __forceinline__ float rl_f(float v, int l) {
  return __int_as_float(__builtin_amdgcn_readlane(__float_as_int(v), l));
}

__global__ __launch_bounds__(TPB) void k_agg(const float* __restrict__ H,
                                             const int* __restrict__ rowptr,
                                             const int* __restrict__ col,
                                             const float* __restrict__ dinv,
                                             const float* __restrict__ bias,
                                             float* __restrict__ OUT, int N) {
  int i = (blockIdx.x * TPB + threadIdx.x) >> 6;
  int lane = threadIdx.x & 63;
  if (i >= N) return;
  float di = dinv[i];
  float acc = H[(size_t)i * 64 + lane] * di * di;  // self-loop
  int beg = rowptr[i], end = rowptr[i + 1];
  for (int c0 = beg; c0 < end; c0 += 64) {
    int m = end - c0;
    if (m > 64) m = 64;
    int jj = c0 + lane;
    int sv = col[jj < end ? jj : beg];
    float nv = di * dinv[sv];
    int t = 0;
    for (; t + 8 <= m; t += 8) {
      int s0 = __builtin_amdgcn_readlane(sv, t + 0);
      int s1 = __builtin_amdgcn_readlane(sv, t + 1);
      int s2 = __builtin_amdgcn_readlane(sv, t + 2);
      int s3 = __builtin_amdgcn_readlane(sv, t + 3);
      int s4 = __builtin_amdgcn_readlane(sv, t + 4);
      int s5 = __builtin_amdgcn_readlane(sv, t + 5);
      int s6 = __builtin_amdgcn_readlane(sv, t + 6);
      int s7 = __builtin_amdgcn_readlane(sv, t + 7);
      float h0 = H[((size_t)s0 << 6) + lane];
      float h1 = H[((size_t)s1 << 6) + lane];
      float h2 = H[((size_t)s2 << 6) + lane];
      float h3 = H[((size_t)s3 << 6) + lane];
      float h4 = H[((size_t)s4 << 6) + lane];
      float h5 = H[((size_t)s5 << 6) + lane];
      float h6 = H[((size_t)s6 << 6) + lane];
      float h7 = H[((size_t)s7 << 6) + lane];
      acc += h0 * rl_f(nv, t + 0);
      acc += h1 * rl_f(nv, t + 1);
      acc += h2 * rl_f(nv, t + 2);
      acc += h3 * rl_f(nv, t + 3);
      acc += h4 * rl_f(nv, t + 4);
      acc += h5 * rl_f(nv, t + 5);
      acc += h6 * rl_f(nv, t + 6);
      acc += h7 * rl_f(nv, t + 7);
    }
    if (t + 4 <= m) {
      int s0 = __builtin_amdgcn_readlane(sv, t + 0);
      int s1 = __builtin_amdgcn_readlane(sv, t + 1);
      int s2 = __builtin_amdgcn_readlane(sv, t + 2);
      int s3 = __builtin_amdgcn_readlane(sv, t + 3);
      float h0 = H[((size_t)s0 << 6) + lane];
      float h1 = H[((size_t)s1 << 6) + lane];
      float h2 = H[((size_t)s2 << 6) + lane];
      float h3 = H[((size_t)s3 << 6) + lane];
      acc += h0 * rl_f(nv, t + 0);
      acc += h1 * rl_f(nv, t + 1);
      acc += h2 * rl_f(nv, t + 2);
      acc += h3 * rl_f(nv, t + 3);
      t += 4;
    }
    for (; t < m; ++t) {
      int s = __builtin_amdgcn_readlane(sv, t);
      acc += H[((size_t)s << 6) + lane] * rl_f(nv, t);
    }
  }
  acc += bias[lane];
  OUT[(size_t)i * 64 + lane] = tanhf(acc);
}

// ---------------- fused MLP head: tanh(A@W1+b1)@W2+b2 ----------------
__global__ __launch_bounds__(TPB) void k_fc(const float* __restrict__ A,
                                            const float* __restrict__ w1,
                                            const float* __restrict__ b1,
                                            const float* __restrict__ w2,
                                            const float* __restrict__ b2,
                                            float* __restrict__ out, int N) {
  __shared__ float sw1t[32 * 64];
  __shared__ float sb1[32];
  __shared__ float sw2[32];
  __shared__ float sA[128 * 65];
  int tid = threadIdx.x;
  for (int i = tid; i < 32 * 64; i += TPB) {
    int j = i >> 6, k = i & 63;
    sw1t[i] = w1[k * 32 + j];
  }
  if (tid < 32) { sb1[tid] = b1[tid]; sw2[tid] = w2[tid]; }
  int base = blockIdx.x * 128;
  for (int i = tid; i < 128 * 64; i += TPB) {
    int r = i >> 6, c = i & 63;
    int g = base + r;
    sA[r * 65 + c] = (g < N) ? A[(size_t)g * 64 + c] : 0.f;
  }
  __syncthreads();
  int r = tid >> 1, q = tid & 1;
  int node = base + r;
  const float* arow = &sA[r * 65];
  float o = 0.f;
  for (int j = q * 16; j < q * 16 + 16; ++j) {
    float accj = sb1[j];
    const float* wrow = &sw1t[j * 64];
#pragma unroll 8
    for (int k = 0; k < 64; ++k) accj += arow[k] * wrow[k];
    o += tanhf(accj) * sw2[j];
  }
  o += __shfl_xor(o, 1);
  if (q == 0 && node < N) out[node] = o + b2[0];
}

extern "C" void kernel_launch(void* const* d_in, const int* in_sizes, int n_in,
                              void* d_out, int out_size, void* d_ws, size_t ws_size,
                              hipStream_t stream) {
  const float* x   = (const float*)d_in[0];
  const int*   ei  = (const int*)d_in[1];
  const float* w1  = (const float*)d_in[2];
  const float* b1  = (const float*)d_in[3];
  const float* w2  = (const float*)d_in[4];
  const float* b2  = (const float*)d_in[5];
  const float* fw1 = (const float*)d_in[6];
  const float* fb1 = (const float*)d_in[7];
  const float* fw2 = (const float*)d_in[8];
  const float* fb2 = (const float*)d_in[9];
  float* out = (float*)d_out;

  int N = in_sizes[0] / 128;
  int E = in_sizes[1] / 2;
  const int* src = ei;
  const int* dst = ei + E;

  const int G   = 256;                 // blocks for bucket passes
  const int NBK = (N + 127) / 128;     // 391 buckets
  const int M   = NBK * G;             // bh entries

  // workspace carve-up (~31 MB total)
  char* p = (char*)d_ws;
  size_t off = 0;
  auto take = [&](size_t bytes) -> void* {
    void* r = p + off;
    off += (bytes + 255) & ~(size_t)255;
    return r;
  };
  int*      cnt    = (int*)take((size_t)N * 4);
  float*    dinv   = (float*)take((size_t)N * 4);
  int*      rowptr = (int*)take((size_t)(N + 1) * 4);
  int*      cursor = (int*)take((size_t)N * 4);
  int*      part   = (int*)take(256 * 4);
  int*      bh     = (int*)take((size_t)M * 4);
  int*      bh_off = (int*)take((size_t)(M + 1) * 4);
  unsigned* e2     = (unsigned*)take((size_t)E * 4);
  int*      col    = (int*)take((size_t)E * 4);
  float*    h      = (float*)take((size_t)N * 64 * 4);
  float*    a      = (float*)take((size_t)N * 64 * 4);
  int*      dummy  = (int*)e2;  // bh-scan cursor output; fully overwritten by k_bscatter after
  (void)ws_size; (void)n_in; (void)out_size;

  int NBn = (N + 1023) / 1024;  // 49 scan blocks for cnt
  int NBm = (M + 1023) / 1024;  // 98 scan blocks for bh

  // graph build: bucket counting-sort
  k_bcount<<<G, TPB, 0, stream>>>(dst, bh, E, NBK);
  k_scan1<<<NBm, TPB, 0, stream>>>(bh, part, M);
  k_scan2<<<1, 64, 0, stream>>>(part, NBm);
  k_scan3<<<NBm, TPB, 0, stream>>>(bh, part, bh_off, dummy, M, E);
  k_bscatter<<<G, TPB, 0, stream>>>(src, dst, bh_off, e2, E, NBK);
  k_cnt<<<NBK, TPB, 0, stream>>>(e2, bh_off, cnt, dinv, N, G);
  k_scan1<<<NBn, TPB, 0, stream>>>(cnt, part, N);
  k_scan2<<<1, 64, 0, stream>>>(part, NBn);
  k_scan3<<<NBn, TPB, 0, stream>>>(cnt, part, rowptr, cursor, N, E);
  k_fill2<<<NBK, TPB, 0, stream>>>(e2, rowptr, cursor, col, N);

  // network
  k_gemm<128><<<640, TPB, 0, stream>>>(x, w1, h, N);
  k_agg<<<(N + 3) / 4, TPB, 0, stream>>>(h, rowptr, col, dinv, b1, a, N);
  k_gemm<64><<<640, TPB, 0, stream>>>(a, w2, h, N);
  k_agg<<<(N + 3) / 4, TPB, 0, stream>>>(h, rowptr, col, dinv, b2, a, N);
  k_fc<<<(N + 127) / 128, TPB, 0, stream>>>(a, fw1, fb1, fw2, fb2, out, N);
}

// Round 4
// 234.278 us; speedup vs baseline: 1.6049x; 1.1677x over previous
//
#include <hip/hip_runtime.h>
#include <math.h>

#define TPB 256
#define NBK_MAX 512   // max dst buckets (128 nodes each)
#define FILL_CAP 4096 // LDS col-buffer capacity per bucket (avg run = 2048)

typedef short bf16x8 __attribute__((ext_vector_type(8)));
typedef float f32x4 __attribute__((ext_vector_type(4)));

__device__ __forceinline__ unsigned short rne_bf16(float f) {
  unsigned u = __float_as_uint(f);
  return (unsigned short)((u + 0x7fffu + ((u >> 16) & 1u)) >> 16);
}
__device__ __forceinline__ float bf16_f(unsigned short v) {
  return __uint_as_float((unsigned)v << 16);
}

// ---------------- pass A: per-block bucket histogram ----------------
__global__ __launch_bounds__(TPB) void k_bcount(const int* __restrict__ dst,
                                                int* __restrict__ bh, int E, int NBK) {
  __shared__ int h[NBK_MAX];
  int tid = threadIdx.x, blk = blockIdx.x, G = gridDim.x;
  for (int b = tid; b < NBK; b += TPB) h[b] = 0;
  __syncthreads();
  int chunk = (E + G - 1) / G, lo = blk * chunk, hi = min(E, lo + chunk);
  for (int e = lo + tid; e < hi; e += TPB) atomicAdd(&h[dst[e] >> 7], 1);
  __syncthreads();
  for (int b = tid; b < NBK; b += TPB) bh[b * G + blk] = h[b];  // bucket-major
}

// ---------------- exclusive scan ----------------
__global__ __launch_bounds__(TPB) void k_scan1(const int* __restrict__ cnt,
                                               int* __restrict__ part, int N) {
  __shared__ int red[TPB];
  int t = threadIdx.x;
  int base = blockIdx.x * 1024 + t * 4;
  int s = 0;
#pragma unroll
  for (int u = 0; u < 4; ++u) { int g = base + u; if (g < N) s += cnt[g]; }
  red[t] = s;
  __syncthreads();
  for (int o = TPB / 2; o > 0; o >>= 1) {
    if (t < o) red[t] += red[t + o];
    __syncthreads();
  }
  if (t == 0) part[blockIdx.x] = red[0];
}

__global__ void k_scan2(int* part, int nb) {
  if (threadIdx.x == 0) {
    int s = 0;
    for (int i = 0; i < nb; ++i) { int v = part[i]; part[i] = s; s += v; }
  }
}

__global__ __launch_bounds__(TPB) void k_scan3(const int* __restrict__ cnt,
                                               const int* __restrict__ part,
                                               int* __restrict__ rowptr,
                                               int* __restrict__ cursor, int N, int E) {
  __shared__ int tsum[TPB];
  int t = threadIdx.x;
  int base = blockIdx.x * 1024 + t * 4;
  int v[4], pre[4], s = 0;
#pragma unroll
  for (int u = 0; u < 4; ++u) {
    int g = base + u;
    v[u] = (g < N) ? cnt[g] : 0;
    pre[u] = s;
    s += v[u];
  }
  tsum[t] = s;
  __syncthreads();
  for (int o = 1; o < TPB; o <<= 1) {
    int xv = (t >= o) ? tsum[t - o] : 0;
    __syncthreads();
    tsum[t] += xv;
    __syncthreads();
  }
  int excl = tsum[t] - s;
  int boff = part[blockIdx.x];
#pragma unroll
  for (int u = 0; u < 4; ++u) {
    int g = base + u;
    if (g < N) {
      int r = boff + excl + pre[u];
      rowptr[g] = r;
      cursor[g] = r;
    }
  }
  if (blockIdx.x == 0 && t == 0) rowptr[N] = E;
}

// ---------------- pass B: scatter edges into bucket-grouped e2 ----------------
__global__ __launch_bounds__(TPB) void k_bscatter(const int* __restrict__ src,
                                                  const int* __restrict__ dst,
                                                  const int* __restrict__ bh_off,
                                                  unsigned* __restrict__ e2,
                                                  int E, int NBK) {
  __shared__ int cur[NBK_MAX];
  int tid = threadIdx.x, blk = blockIdx.x, G = gridDim.x;
  for (int b = tid; b < NBK; b += TPB) cur[b] = bh_off[b * G + blk];
  __syncthreads();
  int chunk = (E + G - 1) / G, lo = blk * chunk, hi = min(E, lo + chunk);
  for (int e = lo + tid; e < hi; e += TPB) {
    int d = dst[e], s = src[e];
    int p = atomicAdd(&cur[d >> 7], 1);
    e2[p] = ((unsigned)s << 7) | (unsigned)(d & 127);
  }
}

// ---------------- per-bucket degree count + dinv ----------------
__global__ __launch_bounds__(TPB) void k_cnt(const unsigned* __restrict__ e2,
                                             const int* __restrict__ bh_off,
                                             int* __restrict__ cnt,
                                             float* __restrict__ dinv,
                                             int N, int G) {
  __shared__ int c[128];
  int tid = threadIdx.x, b = blockIdx.x;
  if (tid < 128) c[tid] = 0;
  __syncthreads();
  int st = bh_off[b * G], en = bh_off[(b + 1) * G];
  for (int i = st + tid; i < en; i += TPB) atomicAdd(&c[e2[i] & 127u], 1);
  __syncthreads();
  if (tid < 128) {
    int node = b * 128 + tid;
    if (node < N) {
      cnt[node] = c[tid];
      dinv[node] = rsqrtf((float)(c[tid] + 1));  // +1 self-loop
    }
  }
}

// ---------------- final CSR fill: LDS scatter, coalesced global dump ----------------
__global__ __launch_bounds__(TPB) void k_fill2(const unsigned* __restrict__ e2,
                                               const int* __restrict__ rowptr,
                                               int* __restrict__ cursor,
                                               int* __restrict__ col, int N) {
  __shared__ int cur[128];
  __shared__ int buf[FILL_CAP];
  int tid = threadIdx.x, b = blockIdx.x;
  int st = rowptr[min(b * 128, N)];
  int en = rowptr[min((b + 1) * 128, N)];
  int len = en - st;
  if (len <= FILL_CAP) {
    if (tid < 128) cur[tid] = rowptr[min(b * 128 + tid, N)] - st;
    __syncthreads();
    for (int i = st + tid; i < en; i += TPB) {
      unsigned v = e2[i];
      int p = atomicAdd(&cur[v & 127u], 1);
      buf[p] = (int)(v >> 7);
    }
    __syncthreads();
    for (int i = tid; i < len; i += TPB) col[st + i] = buf[i];
  } else {
    for (int i = st + tid; i < en; i += TPB) {
      unsigned v = e2[i];
      int node = b * 128 + (int)(v & 127u);
      int p = atomicAdd(&cursor[node], 1);
      col[p] = (int)(v >> 7);
    }
  }
}

// ---------------- W split: W[K][64] fp32 -> WT hi/lo [64][K] bf16 ----------------
__global__ __launch_bounds__(TPB) void k_wsplit(const float* __restrict__ W,
                                                unsigned short* __restrict__ hi,
                                                unsigned short* __restrict__ lo, int K) {
  int i = blockIdx.x * TPB + threadIdx.x;
  if (i < K * 64) {
    int k = i >> 6, n = i & 63;
    float w = W[i];
    unsigned short h = rne_bf16(w);
    hi[n * K + k] = h;
    lo[n * K + k] = rne_bf16(w - bf16_f(h));
  }
}

// ---------------- MFMA GEMM: Hout[N,64](bf16) = A[N,K] @ W[K,64] ----------------
// Split-bf16: A*W ~= Ahi*Whi + Ahi*Wlo + Alo*Whi (residual ~2^-18).
// Block = 4 waves, each wave a 16-node strip (full 64 output cols).
// B-frags from LDS (pad 8 shorts -> conflict-free b128: bank-quad=(n+oct)%8).
template <int K, bool AF32>
__global__ __launch_bounds__(TPB) void k_mm(const void* __restrict__ Ap,
                                            const unsigned short* __restrict__ WThi,
                                            const unsigned short* __restrict__ WTlo,
                                            unsigned short* __restrict__ Hout, int N) {
  constexpr int P = K + 8;  // LDS pitch (bf16 elems); byte pitch multiple of 16
  __shared__ unsigned short sHi[64 * P];
  __shared__ unsigned short sLo[64 * P];
  int tid = threadIdx.x;
  constexpr int CH = 64 * K / 8;  // 16B chunks per matrix
  for (int i = tid; i < CH; i += TPB) {
    int n = i / (K / 8), ko = i % (K / 8);
    *(int4*)(sHi + n * P + ko * 8) = *(const int4*)(WThi + n * K + ko * 8);
    *(int4*)(sLo + n * P + ko * 8) = *(const int4*)(WTlo + n * K + ko * 8);
  }
  __syncthreads();
  int wave = tid >> 6, lane = tid & 63;
  int oct = lane >> 4, l15 = lane & 15;
  int base = blockIdx.x * 64 + wave * 16;
  int arow = base + l15;
  if (arow >= N) arow = N - 1;
  f32x4 acc[4] = {};
#pragma unroll
  for (int s = 0; s < K / 32; ++s) {
    bf16x8 ahi, alo;
    if (AF32) {
      const float* ap = (const float*)Ap + (size_t)arow * K + s * 32 + oct * 8;
      float4 f0 = *(const float4*)ap;
      float4 f1 = *(const float4*)(ap + 4);
      float fv[8] = {f0.x, f0.y, f0.z, f0.w, f1.x, f1.y, f1.z, f1.w};
#pragma unroll
      for (int j = 0; j < 8; ++j) {
        unsigned short hb = rne_bf16(fv[j]);
        ahi[j] = (short)hb;
        alo[j] = (short)rne_bf16(fv[j] - bf16_f(hb));
      }
    } else {
      ahi = *(const bf16x8*)((const unsigned short*)Ap + (size_t)arow * K + s * 32 + oct * 8);
    }
#pragma unroll
    for (int t = 0; t < 4; ++t) {
      bf16x8 bhi = *(const bf16x8*)(sHi + (t * 16 + l15) * P + s * 32 + oct * 8);
      bf16x8 blo = *(const bf16x8*)(sLo + (t * 16 + l15) * P + s * 32 + oct * 8);
      acc[t] = __builtin_amdgcn_mfma_f32_16x16x32_bf16(ahi, bhi, acc[t], 0, 0, 0);
      acc[t] = __builtin_amdgcn_mfma_f32_16x16x32_bf16(ahi, blo, acc[t], 0, 0, 0);
      if (AF32)
        acc[t] = __builtin_amdgcn_mfma_f32_16x16x32_bf16(alo, bhi, acc[t], 0, 0, 0);
    }
  }
  // epilogue: D row = oct*4+r, col = t*16+l15
#pragma unroll
  for (int r = 0; r < 4; ++r) {
    int row = base + oct * 4 + r;
    if (row < N) {
#pragma unroll
      for (int t = 0; t < 4; ++t)
        Hout[(size_t)row * 64 + t * 16 + l15] = rne_bf16(acc[t][r]);
    }
  }
}

// ---------------- pull aggregation (bf16 H/OUT): wave per node, lane = feature ----------------
__device__ __forceinline__ float rl_f(float v, int l) {
  return __int_as_float(__builtin_amdgcn_readlane(__float_as_int(v), l));
}

__global__ __launch_bounds__(TPB) void k_agg(const unsigned short* __restrict__ H,
                                             const int* __restrict__ rowptr,
                                             const int* __restrict__ col,
                                             const float* __restrict__ dinv,
                                             const float* __restrict__ bias,
                                             unsigned short* __restrict__ OUT, int N) {
  int i = (blockIdx.x * TPB + threadIdx.x) >> 6;
  int lane = threadIdx.x & 63;
  if (i >= N) return;
  float di = dinv[i];
  float acc = bf16_f(H[((size_t)i << 6) + lane]) * di * di;  // self-loop
  int beg = rowptr[i], end = rowptr[i + 1];
  for (int c0 = beg; c0 < end; c0 += 64) {
    int m = end - c0;
    if (m > 64) m = 64;
    int jj = c0 + lane;
    int sv = col[jj < end ? jj : beg];
    float nv = di * dinv[sv];
    int t = 0;
    for (; t + 8 <= m; t += 8) {
      int s0 = __builtin_amdgcn_readlane(sv, t + 0);
      int s1 = __builtin_amdgcn_readlane(sv, t + 1);
      int s2 = __builtin_amdgcn_readlane(sv, t + 2);
      int s3 = __builtin_amdgcn_readlane(sv, t + 3);
      int s4 = __builtin_amdgcn_readlane(sv, t + 4);
      int s5 = __builtin_amdgcn_readlane(sv, t + 5);
      int s6 = __builtin_amdgcn_readlane(sv, t + 6);
      int s7 = __builtin_amdgcn_readlane(sv, t + 7);
      float h0 = bf16_f(H[((size_t)s0 << 6) + lane]);
      float h1 = bf16_f(H[((size_t)s1 << 6) + lane]);
      float h2 = bf16_f(H[((size_t)s2 << 6) + lane]);
      float h3 = bf16_f(H[((size_t)s3 << 6) + lane]);
      float h4 = bf16_f(H[((size_t)s4 << 6) + lane]);
      float h5 = bf16_f(H[((size_t)s5 << 6) + lane]);
      float h6 = bf16_f(H[((size_t)s6 << 6) + lane]);
      float h7 = bf16_f(H[((size_t)s7 << 6) + lane]);
      acc += h0 * rl_f(nv, t + 0);
      acc += h1 * rl_f(nv, t + 1);
      acc += h2 * rl_f(nv, t + 2);
      acc += h3 * rl_f(nv, t + 3);
      acc += h4 * rl_f(nv, t + 4);
      acc += h5 * rl_f(nv, t + 5);
      acc += h6 * rl_f(nv, t + 6);
      acc += h7 * rl_f(nv, t + 7);
    }
    if (t + 4 <= m) {
      int s0 = __builtin_amdgcn_readlane(sv, t + 0);
      int s1 = __builtin_amdgcn_readlane(sv, t + 1);
      int s2 = __builtin_amdgcn_readlane(sv, t + 2);
      int s3 = __builtin_amdgcn_readlane(sv, t + 3);
      float h0 = bf16_f(H[((size_t)s0 << 6) + lane]);
      float h1 = bf16_f(H[((size_t)s1 << 6) + lane]);
      float h2 = bf16_f(H[((size_t)s2 << 6) + lane]);
      float h3 = bf16_f(H[((size_t)s3 << 6) + lane]);
      acc += h0 * rl_f(nv, t + 0);
      acc += h1 * rl_f(nv, t + 1);
      acc += h2 * rl_f(nv, t + 2);
      acc += h3 * rl_f(nv, t + 3);
      t += 4;
    }
    for (; t < m; ++t) {
      int s = __builtin_amdgcn_readlane(sv, t);
      acc += bf16_f(H[((size_t)s << 6) + lane]) * rl_f(nv, t);
    }
  }
  acc += bias[lane];
  OUT[((size_t)i << 6) + lane] = rne_bf16(tanhf(acc));
}

// ---------------- fused MLP head: tanh(A@W1+b1)@W2+b2 (A in bf16) ----------------
__global__ __launch_bounds__(TPB) void k_fc(const unsigned short* __restrict__ A,
                                            const float* __restrict__ w1,
                                            const float* __restrict__ b1,
                                            const float* __restrict__ w2,
                                            const float* __restrict__ b2,
                                            float* __restrict__ out, int N) {
  __shared__ float sw1t[32 * 64];
  __shared__ float sb1[32];
  __shared__ float sw2[32];
  __shared__ float sA[128 * 65];
  int tid = threadIdx.x;
  for (int i = tid; i < 32 * 64; i += TPB) {
    int j = i >> 6, k = i & 63;
    sw1t[i] = w1[k * 32 + j];
  }
  if (tid < 32) { sb1[tid] = b1[tid]; sw2[tid] = w2[tid]; }
  int base = blockIdx.x * 128;
  for (int i = tid; i < 128 * 64; i += TPB) {
    int r = i >> 6, c = i & 63;
    int g = base + r;
    sA[r * 65 + c] = (g < N) ? bf16_f(A[(size_t)g * 64 + c]) : 0.f;
  }
  __syncthreads();
  int r = tid >> 1, q = tid & 1;
  int node = base + r;
  const float* arow = &sA[r * 65];
  float o = 0.f;
  for (int j = q * 16; j < q * 16 + 16; ++j) {
    float accj = sb1[j];
    const float* wrow = &sw1t[j * 64];
#pragma unroll 8
    for (int k = 0; k < 64; ++k) accj += arow[k] * wrow[k];
    o += tanhf(accj) * sw2[j];
  }
  o += __shfl_xor(o, 1);
  if (q == 0 && node < N) out[node] = o + b2[0];
}

extern "C" void kernel_launch(void* const* d_in, const int* in_sizes, int n_in,
                              void* d_out, int out_size, void* d_ws, size_t ws_size,
                              hipStream_t stream) {
  const float* x   = (const float*)d_in[0];
  const int*   ei  = (const int*)d_in[1];
  const float* w1  = (const float*)d_in[2];
  const float* b1  = (const float*)d_in[3];
  const float* w2  = (const float*)d_in[4];
  const float* b2  = (const float*)d_in[5];
  const float* fw1 = (const float*)d_in[6];
  const float* fb1 = (const float*)d_in[7];
  const float* fw2 = (const float*)d_in[8];
  const float* fb2 = (const float*)d_in[9];
  float* out = (float*)d_out;

  int N = in_sizes[0] / 128;
  int E = in_sizes[1] / 2;
  const int* src = ei;
  const int* dst = ei + E;

  const int G   = 256;
  const int NBK = (N + 127) / 128;
  const int M   = NBK * G;

  char* p = (char*)d_ws;
  size_t off = 0;
  auto take = [&](size_t bytes) -> void* {
    void* r = p + off;
    off += (bytes + 255) & ~(size_t)255;
    return r;
  };
  int*            cnt    = (int*)take((size_t)N * 4);
  float*          dinv   = (float*)take((size_t)N * 4);
  int*            rowptr = (int*)take((size_t)(N + 1) * 4);
  int*            cursor = (int*)take((size_t)N * 4);
  int*            part   = (int*)take(256 * 4);
  int*            bh     = (int*)take((size_t)M * 4);
  int*            bh_off = (int*)take((size_t)(M + 1) * 4);
  unsigned*       e2     = (unsigned*)take((size_t)E * 4);
  int*            col    = (int*)take((size_t)E * 4);
  unsigned short* wt1hi  = (unsigned short*)take(64 * 128 * 2);
  unsigned short* wt1lo  = (unsigned short*)take(64 * 128 * 2);
  unsigned short* wt2hi  = (unsigned short*)take(64 * 64 * 2);
  unsigned short* wt2lo  = (unsigned short*)take(64 * 64 * 2);
  unsigned short* h      = (unsigned short*)take((size_t)N * 64 * 2);
  unsigned short* a      = (unsigned short*)take((size_t)N * 64 * 2);
  int*            dummy  = (int*)e2;  // bh-scan cursor out; overwritten by k_bscatter
  (void)ws_size; (void)n_in; (void)out_size;

  int NBn = (N + 1023) / 1024;
  int NBm = (M + 1023) / 1024;

  // graph build: bucket counting-sort
  k_bcount<<<G, TPB, 0, stream>>>(dst, bh, E, NBK);
  k_scan1<<<NBm, TPB, 0, stream>>>(bh, part, M);
  k_scan2<<<1, 64, 0, stream>>>(part, NBm);
  k_scan3<<<NBm, TPB, 0, stream>>>(bh, part, bh_off, dummy, M, E);
  k_bscatter<<<G, TPB, 0, stream>>>(src, dst, bh_off, e2, E, NBK);
  k_cnt<<<NBK, TPB, 0, stream>>>(e2, bh_off, cnt, dinv, N, G);
  k_scan1<<<NBn, TPB, 0, stream>>>(cnt, part, N);
  k_scan2<<<1, 64, 0, stream>>>(part, NBn);
  k_scan3<<<NBn, TPB, 0, stream>>>(cnt, part, rowptr, cursor, N, E);
  k_fill2<<<NBK, TPB, 0, stream>>>(e2, rowptr, cursor, col, N);

  // weight splits (tiny)
  k_wsplit<<<32, TPB, 0, stream>>>(w1, wt1hi, wt1lo, 128);
  k_wsplit<<<16, TPB, 0, stream>>>(w2, wt2hi, wt2lo, 64);

  // network
  int gmm = (N + 63) / 64;
  k_mm<128, true><<<gmm, TPB, 0, stream>>>(x, wt1hi, wt1lo, h, N);
  k_agg<<<(N + 3) / 4, TPB, 0, stream>>>(h, rowptr, col, dinv, b1, a, N);
  k_mm<64, false><<<gmm, TPB, 0, stream>>>(a, wt2hi, wt2lo, h, N);
  k_agg<<<(N + 3) / 4, TPB, 0, stream>>>(h, rowptr, col, dinv, b2, a, N);
  k_fc<<<(N + 127) / 128, TPB, 0, stream>>>(a, fw1, fb1, fw2, fb2, out, N);
}

// Round 5
// 218.215 us; speedup vs baseline: 1.7230x; 1.0736x over previous
//
#include <hip/hip_runtime.h>
#include <math.h>

#define TPB 256
#define NBK_MAX 512   // max dst buckets (128 nodes each)
#define FILL_CAP 4096 // LDS col-buffer per bucket (avg run 2046, std ~45 -> 45 sigma)
#define SC_CH 16      // register-held edges per thread in k_bscatter

typedef short bf16x8 __attribute__((ext_vector_type(8)));
typedef float f32x4 __attribute__((ext_vector_type(4)));

__device__ __forceinline__ unsigned short rne_bf16(float f) {
  unsigned u = __float_as_uint(f);
  return (unsigned short)((u + 0x7fffu + ((u >> 16) & 1u)) >> 16);
}
__device__ __forceinline__ float bf16_f(unsigned short v) {
  return __uint_as_float((unsigned)v << 16);
}

// ---------------- build 1: bucket totals (LDS hist -> one global add per bucket) ----------------
__global__ __launch_bounds__(TPB) void k_bcount(const int* __restrict__ dst,
                                                int* __restrict__ btot, int E, int NBK) {
  __shared__ int h[NBK_MAX];
  int tid = threadIdx.x, blk = blockIdx.x, G = gridDim.x;
  for (int b = tid; b < NBK; b += TPB) h[b] = 0;
  __syncthreads();
  int chunk = (E + G - 1) / G, lo = blk * chunk, hi = min(E, lo + chunk);
  for (int e = lo + tid; e < hi; e += TPB) atomicAdd(&h[dst[e] >> 7], 1);
  __syncthreads();
  for (int b = tid; b < NBK; b += TPB)
    if (h[b]) atomicAdd(&btot[b], h[b]);
}

// ---------------- build 2: exclusive scan of 391 bucket totals (single block) ----------------
// bstart[b] doubles as rowptr at node granularity b*128 (e2 is node-ordered by bucket).
__global__ __launch_bounds__(TPB) void k_bstart(const int* __restrict__ btot,
                                                int* __restrict__ bstart,
                                                int* __restrict__ gcur,
                                                int* __restrict__ rowptr,
                                                int NBK, int N, int E) {
  __shared__ int sc[TPB];
  int t = threadIdx.x;
  int i0 = 2 * t, i1 = 2 * t + 1;
  int a0 = (i0 < NBK) ? btot[i0] : 0;
  int a1 = (i1 < NBK) ? btot[i1] : 0;
  int s = a0 + a1;
  sc[t] = s;
  __syncthreads();
  for (int o = 1; o < TPB; o <<= 1) {
    int v = (t >= o) ? sc[t - o] : 0;
    __syncthreads();
    sc[t] += v;
    __syncthreads();
  }
  int excl = sc[t] - s;
  if (i0 < NBK) { bstart[i0] = excl;      gcur[i0] = excl; }
  if (i1 < NBK) { bstart[i1] = excl + a0; gcur[i1] = excl + a0; }
  if (t == 0) { bstart[NBK] = E; rowptr[N] = E; }
}

// ---------------- build 3: scatter edges into bucket-grouped e2 ----------------
// Per-tile: LDS count -> one atomic range-reservation per bucket -> LDS-ranked
// scatter. Each reserved range is written by exactly one block (contiguous),
// preserving the no-cross-XCD-line-ping-pong property.
__global__ __launch_bounds__(TPB) void k_bscatter(const int* __restrict__ src,
                                                  const int* __restrict__ dst,
                                                  int* __restrict__ gcur,
                                                  unsigned* __restrict__ e2,
                                                  int E, int NBK) {
  __shared__ int h[NBK_MAX];
  __shared__ int base[NBK_MAX];
  int tid = threadIdx.x, blk = blockIdx.x, G = gridDim.x;
  int chunk = (E + G - 1) / G, lo = blk * chunk, hi = min(E, lo + chunk);
  for (int t0 = lo; t0 < hi; t0 += TPB * SC_CH) {
    int sv[SC_CH], dv[SC_CH];
    for (int b = tid; b < NBK; b += TPB) h[b] = 0;
    __syncthreads();
#pragma unroll
    for (int u = 0; u < SC_CH; ++u) {
      int e = t0 + u * TPB + tid;
      if (e < hi) {
        dv[u] = dst[e];
        sv[u] = src[e];
        atomicAdd(&h[dv[u] >> 7], 1);
      } else {
        dv[u] = -1;
      }
    }
    __syncthreads();
    for (int b = tid; b < NBK; b += TPB) {
      int c = h[b];
      base[b] = c ? atomicAdd(&gcur[b], c) : 0;
    }
    __syncthreads();
    for (int b = tid; b < NBK; b += TPB) h[b] = 0;
    __syncthreads();
#pragma unroll
    for (int u = 0; u < SC_CH; ++u) {
      if (dv[u] >= 0) {
        int bk = dv[u] >> 7;
        int r = atomicAdd(&h[bk], 1);
        e2[base[bk] + r] = ((unsigned)sv[u] << 7) | (unsigned)(dv[u] & 127);
      }
    }
    __syncthreads();
  }
}

// ---------------- build 4: fused per-bucket count + local scan + rowptr/dinv + CSR fill ----------------
__global__ __launch_bounds__(TPB) void k_build(const unsigned* __restrict__ e2,
                                               const int* __restrict__ bstart,
                                               int* __restrict__ rowptr,
                                               float* __restrict__ dinv,
                                               int* __restrict__ col, int N) {
  __shared__ int c[128], sc[128], cur[128];
  __shared__ int buf[FILL_CAP];
  int tid = threadIdx.x, b = blockIdx.x;
  int st = bstart[b], en = bstart[b + 1], len = en - st;
  if (tid < 128) c[tid] = 0;
  __syncthreads();
  for (int i = st + tid; i < en; i += TPB) atomicAdd(&c[e2[i] & 127u], 1);
  __syncthreads();
  if (tid < 128) sc[tid] = c[tid];
  __syncthreads();
  for (int o = 1; o < 128; o <<= 1) {
    int v = (tid >= o && tid < 128) ? sc[tid - o] : 0;
    __syncthreads();
    if (tid < 128) sc[tid] += v;
    __syncthreads();
  }
  if (tid < 128) {
    int excl = sc[tid] - c[tid];
    cur[tid] = excl;
    int node = b * 128 + tid;
    if (node < N) {
      rowptr[node] = st + excl;
      dinv[node] = rsqrtf((float)(c[tid] + 1));  // +1 self-loop
    }
  }
  __syncthreads();
  if (len <= FILL_CAP) {
    for (int i = st + tid; i < en; i += TPB) {
      unsigned v = e2[i];
      int p = atomicAdd(&cur[v & 127u], 1);
      buf[p] = (int)(v >> 7);
    }
    __syncthreads();
    for (int i = tid; i < len; i += TPB) col[st + i] = buf[i];
  } else {  // safety fallback
    for (int i = st + tid; i < en; i += TPB) {
      unsigned v = e2[i];
      int p = atomicAdd(&cur[v & 127u], 1);
      col[st + p] = (int)(v >> 7);
    }
  }
}

// ---------------- W split (both layers in one launch) ----------------
__global__ __launch_bounds__(TPB) void k_wsplit2(const float* __restrict__ W1,
                                                 const float* __restrict__ W2,
                                                 unsigned short* __restrict__ hi1,
                                                 unsigned short* __restrict__ lo1,
                                                 unsigned short* __restrict__ hi2,
                                                 unsigned short* __restrict__ lo2) {
  int i = blockIdx.x * TPB + threadIdx.x;
  if (i < 128 * 64) {
    int k = i >> 6, n = i & 63;
    float w = W1[i];
    unsigned short h = rne_bf16(w);
    hi1[n * 128 + k] = h;
    lo1[n * 128 + k] = rne_bf16(w - bf16_f(h));
  } else if (i < 128 * 64 + 64 * 64) {
    int j = i - 128 * 64;
    int k = j >> 6, n = j & 63;
    float w = W2[j];
    unsigned short h = rne_bf16(w);
    hi2[n * 64 + k] = h;
    lo2[n * 64 + k] = rne_bf16(w - bf16_f(h));
  }
}

// ---------------- MFMA GEMM: Hout[N,64](bf16) = A[N,K] @ W[K,64] ----------------
// Split-bf16: A*W ~= Ahi*Whi + Ahi*Wlo + Alo*Whi (residual ~2^-18).
template <int K, bool AF32>
__global__ __launch_bounds__(TPB) void k_mm(const void* __restrict__ Ap,
                                            const unsigned short* __restrict__ WThi,
                                            const unsigned short* __restrict__ WTlo,
                                            unsigned short* __restrict__ Hout, int N) {
  constexpr int P = K + 8;  // LDS pitch (bf16); conflict-free b128 frag reads
  __shared__ unsigned short sHi[64 * P];
  __shared__ unsigned short sLo[64 * P];
  int tid = threadIdx.x;
  constexpr int CH = 64 * K / 8;
  for (int i = tid; i < CH; i += TPB) {
    int n = i / (K / 8), ko = i % (K / 8);
    *(int4*)(sHi + n * P + ko * 8) = *(const int4*)(WThi + n * K + ko * 8);
    *(int4*)(sLo + n * P + ko * 8) = *(const int4*)(WTlo + n * K + ko * 8);
  }
  __syncthreads();
  int wave = tid >> 6, lane = tid & 63;
  int oct = lane >> 4, l15 = lane & 15;
  int base = blockIdx.x * 64 + wave * 16;
  int arow = base + l15;
  if (arow >= N) arow = N - 1;
  f32x4 acc[4] = {};
#pragma unroll
  for (int s = 0; s < K / 32; ++s) {
    bf16x8 ahi, alo;
    if (AF32) {
      const float* ap = (const float*)Ap + (size_t)arow * K + s * 32 + oct * 8;
      float4 f0 = *(const float4*)ap;
      float4 f1 = *(const float4*)(ap + 4);
      float fv[8] = {f0.x, f0.y, f0.z, f0.w, f1.x, f1.y, f1.z, f1.w};
#pragma unroll
      for (int j = 0; j < 8; ++j) {
        unsigned short hb = rne_bf16(fv[j]);
        ahi[j] = (short)hb;
        alo[j] = (short)rne_bf16(fv[j] - bf16_f(hb));
      }
    } else {
      ahi = *(const bf16x8*)((const unsigned short*)Ap + (size_t)arow * K + s * 32 + oct * 8);
    }
#pragma unroll
    for (int t = 0; t < 4; ++t) {
      bf16x8 bhi = *(const bf16x8*)(sHi + (t * 16 + l15) * P + s * 32 + oct * 8);
      bf16x8 blo = *(const bf16x8*)(sLo + (t * 16 + l15) * P + s * 32 + oct * 8);
      acc[t] = __builtin_amdgcn_mfma_f32_16x16x32_bf16(ahi, bhi, acc[t], 0, 0, 0);
      acc[t] = __builtin_amdgcn_mfma_f32_16x16x32_bf16(ahi, blo, acc[t], 0, 0, 0);
      if (AF32)
        acc[t] = __builtin_amdgcn_mfma_f32_16x16x32_bf16(alo, bhi, acc[t], 0, 0, 0);
    }
  }
#pragma unroll
  for (int r = 0; r < 4; ++r) {
    int row = base + oct * 4 + r;
    if (row < N) {
#pragma unroll
      for (int t = 0; t < 4; ++t)
        Hout[(size_t)row * 64 + t * 16 + l15] = rne_bf16(acc[t][r]);
    }
  }
}

// ---------------- pull aggregation (bf16 H/OUT): wave per node, lane = feature ----------------
__device__ __forceinline__ float rl_f(float v, int l) {
  return __int_as_float(__builtin_amdgcn_readlane(__float_as_int(v), l));
}

__global__ __launch_bounds__(TPB) void k_agg(const unsigned short* __restrict__ H,
                                             const int* __restrict__ rowptr,
                                             const int* __restrict__ col,
                                             const float* __restrict__ dinv,
                                             const float* __restrict__ bias,
                                             unsigned short* __restrict__ OUT, int N) {
  int i = (blockIdx.x * TPB + threadIdx.x) >> 6;
  int lane = threadIdx.x & 63;
  if (i >= N) return;
  float di = dinv[i];
  float acc = bf16_f(H[((size_t)i << 6) + lane]) * di * di;  // self-loop
  int beg = rowptr[i], end = rowptr[i + 1];
  for (int c0 = beg; c0 < end; c0 += 64) {
    int m = end - c0;
    if (m > 64) m = 64;
    int jj = c0 + lane;
    int sv = col[jj < end ? jj : beg];
    float nv = di * dinv[sv];
    int t = 0;
    for (; t + 8 <= m; t += 8) {
      int s0 = __builtin_amdgcn_readlane(sv, t + 0);
      int s1 = __builtin_amdgcn_readlane(sv, t + 1);
      int s2 = __builtin_amdgcn_readlane(sv, t + 2);
      int s3 = __builtin_amdgcn_readlane(sv, t + 3);
      int s4 = __builtin_amdgcn_readlane(sv, t + 4);
      int s5 = __builtin_amdgcn_readlane(sv, t + 5);
      int s6 = __builtin_amdgcn_readlane(sv, t + 6);
      int s7 = __builtin_amdgcn_readlane(sv, t + 7);
      float h0 = bf16_f(H[((size_t)s0 << 6) + lane]);
      float h1 = bf16_f(H[((size_t)s1 << 6) + lane]);
      float h2 = bf16_f(H[((size_t)s2 << 6) + lane]);
      float h3 = bf16_f(H[((size_t)s3 << 6) + lane]);
      float h4 = bf16_f(H[((size_t)s4 << 6) + lane]);
      float h5 = bf16_f(H[((size_t)s5 << 6) + lane]);
      float h6 = bf16_f(H[((size_t)s6 << 6) + lane]);
      float h7 = bf16_f(H[((size_t)s7 << 6) + lane]);
      acc += h0 * rl_f(nv, t + 0);
      acc += h1 * rl_f(nv, t + 1);
      acc += h2 * rl_f(nv, t + 2);
      acc += h3 * rl_f(nv, t + 3);
      acc += h4 * rl_f(nv, t + 4);
      acc += h5 * rl_f(nv, t + 5);
      acc += h6 * rl_f(nv, t + 6);
      acc += h7 * rl_f(nv, t + 7);
    }
    if (t + 4 <= m) {
      int s0 = __builtin_amdgcn_readlane(sv, t + 0);
      int s1 = __builtin_amdgcn_readlane(sv, t + 1);
      int s2 = __builtin_amdgcn_readlane(sv, t + 2);
      int s3 = __builtin_amdgcn_readlane(sv, t + 3);
      float h0 = bf16_f(H[((size_t)s0 << 6) + lane]);
      float h1 = bf16_f(H[((size_t)s1 << 6) + lane]);
      float h2 = bf16_f(H[((size_t)s2 << 6) + lane]);
      float h3 = bf16_f(H[((size_t)s3 << 6) + lane]);
      acc += h0 * rl_f(nv, t + 0);
      acc += h1 * rl_f(nv, t + 1);
      acc += h2 * rl_f(nv, t + 2);
      acc += h3 * rl_f(nv, t + 3);
      t += 4;
    }
    for (; t < m; ++t) {
      int s = __builtin_amdgcn_readlane(sv, t);
      acc += bf16_f(H[((size_t)s << 6) + lane]) * rl_f(nv, t);
    }
  }
  acc += bias[lane];
  OUT[((size_t)i << 6) + lane] = rne_bf16(tanhf(acc));
}

// ---------------- fused MLP head: tanh(A@W1+b1)@W2+b2 (A in bf16) ----------------
__global__ __launch_bounds__(TPB) void k_fc(const unsigned short* __restrict__ A,
                                            const float* __restrict__ w1,
                                            const float* __restrict__ b1,
                                            const float* __restrict__ w2,
                                            const float* __restrict__ b2,
                                            float* __restrict__ out, int N) {
  __shared__ float sw1t[32 * 64];
  __shared__ float sb1[32];
  __shared__ float sw2[32];
  __shared__ float sA[128 * 65];
  int tid = threadIdx.x;
  for (int i = tid; i < 32 * 64; i += TPB) {
    int j = i >> 6, k = i & 63;
    sw1t[i] = w1[k * 32 + j];
  }
  if (tid < 32) { sb1[tid] = b1[tid]; sw2[tid] = w2[tid]; }
  int base = blockIdx.x * 128;
  for (int i = tid; i < 128 * 64; i += TPB) {
    int r = i >> 6, c = i & 63;
    int g = base + r;
    sA[r * 65 + c] = (g < N) ? bf16_f(A[(size_t)g * 64 + c]) : 0.f;
  }
  __syncthreads();
  int r = tid >> 1, q = tid & 1;
  int node = base + r;
  const float* arow = &sA[r * 65];
  float o = 0.f;
  for (int j = q * 16; j < q * 16 + 16; ++j) {
    float accj = sb1[j];
    const float* wrow = &sw1t[j * 64];
#pragma unroll 8
    for (int k = 0; k < 64; ++k) accj += arow[k] * wrow[k];
    o += tanhf(accj) * sw2[j];
  }
  o += __shfl_xor(o, 1);
  if (q == 0 && node < N) out[node] = o + b2[0];
}

extern "C" void kernel_launch(void* const* d_in, const int* in_sizes, int n_in,
                              void* d_out, int out_size, void* d_ws, size_t ws_size,
                              hipStream_t stream) {
  const float* x   = (const float*)d_in[0];
  const int*   ei  = (const int*)d_in[1];
  const float* w1  = (const float*)d_in[2];
  const float* b1  = (const float*)d_in[3];
  const float* w2  = (const float*)d_in[4];
  const float* b2  = (const float*)d_in[5];
  const float* fw1 = (const float*)d_in[6];
  const float* fb1 = (const float*)d_in[7];
  const float* fw2 = (const float*)d_in[8];
  const float* fb2 = (const float*)d_in[9];
  float* out = (float*)d_out;

  int N = in_sizes[0] / 128;
  int E = in_sizes[1] / 2;
  const int* src = ei;
  const int* dst = ei + E;

  const int G   = 256;                // blocks for bucket passes
  const int NBK = (N + 127) / 128;    // 391 buckets

  char* p = (char*)d_ws;
  size_t off = 0;
  auto take = [&](size_t bytes) -> void* {
    void* r = p + off;
    off += (bytes + 255) & ~(size_t)255;
    return r;
  };
  int*            btot   = (int*)take((size_t)NBK * 4);
  int*            bstart = (int*)take((size_t)(NBK + 1) * 4);
  int*            gcur   = (int*)take((size_t)NBK * 4);
  int*            rowptr = (int*)take((size_t)(N + 1) * 4);
  float*          dinv   = (float*)take((size_t)N * 4);
  unsigned*       e2     = (unsigned*)take((size_t)E * 4);
  int*            col    = (int*)take((size_t)E * 4);
  unsigned short* wt1hi  = (unsigned short*)take(64 * 128 * 2);
  unsigned short* wt1lo  = (unsigned short*)take(64 * 128 * 2);
  unsigned short* wt2hi  = (unsigned short*)take(64 * 64 * 2);
  unsigned short* wt2lo  = (unsigned short*)take(64 * 64 * 2);
  unsigned short* h      = (unsigned short*)take((size_t)N * 64 * 2);
  unsigned short* a      = (unsigned short*)take((size_t)N * 64 * 2);
  (void)ws_size; (void)n_in; (void)out_size;

  // graph build: 4 kernels + tiny memset
  hipMemsetAsync(btot, 0, (size_t)NBK * 4, stream);
  k_bcount<<<G, TPB, 0, stream>>>(dst, btot, E, NBK);
  k_bstart<<<1, TPB, 0, stream>>>(btot, bstart, gcur, rowptr, NBK, N, E);
  k_bscatter<<<G, TPB, 0, stream>>>(src, dst, gcur, e2, E, NBK);
  k_build<<<NBK, TPB, 0, stream>>>(e2, bstart, rowptr, dinv, col, N);

  // weight splits (one launch, both layers)
  k_wsplit2<<<48, TPB, 0, stream>>>(w1, w2, wt1hi, wt1lo, wt2hi, wt2lo);

  // network
  int gmm = (N + 63) / 64;
  k_mm<128, true><<<gmm, TPB, 0, stream>>>(x, wt1hi, wt1lo, h, N);
  k_agg<<<(N + 3) / 4, TPB, 0, stream>>>(h, rowptr, col, dinv, b1, a, N);
  k_mm<64, false><<<gmm, TPB, 0, stream>>>(a, wt2hi, wt2lo, h, N);
  k_agg<<<(N + 3) / 4, TPB, 0, stream>>>(h, rowptr, col, dinv, b2, a, N);
  k_fc<<<(N + 127) / 128, TPB, 0, stream>>>(a, fw1, fb1, fw2, fb2, out, N);
}